// Round 14
// baseline (724.477 us; speedup 1.0000x reference)
//
#include <hip/hip_runtime.h>
#include <hip/hip_bf16.h>

using bf16 = __hip_bfloat16;
typedef __bf16 bf16x8 __attribute__((ext_vector_type(8)));
typedef float f32x4 __attribute__((ext_vector_type(4)));

// Sizes (fixed): B=8 S=32 N=64 F_NODE=32 TRI=2016 DIN=2048 H=4 DOUT=256 R=1024
// OUT=2016, G=B*S=256 graphs

__device__ __forceinline__ void unp2(unsigned int u, float& a, float& b) {
  a = __uint_as_float(u << 16);
  b = __uint_as_float(u & 0xffff0000u);
}

__device__ __forceinline__ bf16x8 cvt8(float4 a, float4 b) {
  bf16x8 r;
  r[0] = (__bf16)a.x; r[1] = (__bf16)a.y; r[2] = (__bf16)a.z; r[3] = (__bf16)a.w;
  r[4] = (__bf16)b.x; r[5] = (__bf16)b.y; r[6] = (__bf16)b.z; r[7] = (__bf16)b.w;
  return r;
}

// ---------------------------------------------------------------------------
// One-shot fp32 -> bf16 conversion of the three RNN weight matrices.
// ---------------------------------------------------------------------------
__global__ __launch_bounds__(256) void wcvt_k(const float* __restrict__ a,
                                              const float* __restrict__ b,
                                              const float* __restrict__ c,
                                              __bf16* __restrict__ A,
                                              __bf16* __restrict__ B,
                                              __bf16* __restrict__ C) {
  const int i = (blockIdx.x * 256 + threadIdx.x) * 8;
  float4 x0 = *(const float4*)&a[i], x1 = *(const float4*)&a[i + 4];
  *(bf16x8*)&A[i] = cvt8(x0, x1);
  float4 y0_ = *(const float4*)&b[i], y1_ = *(const float4*)&b[i + 4];
  *(bf16x8*)&B[i] = cvt8(y0_, y1_);
  float4 z0 = *(const float4*)&c[i], z1 = *(const float4*)&c[i + 4];
  *(bf16x8*)&C[i] = cvt8(z0, z1);
}

// ---------------------------------------------------------------------------
// X0 GEMM, BK=64 line-complete bursts, NO-SPILL build.
// __launch_bounds__(256, 2): 2 waves/EU -> 256-VGPR budget; acc(128) +
// A-prefetch(32) + B-prefetch(32) + addressing fits without scratch.
// A: [256,K] bf16 — thread t loads row t's 128B chunk (8 uint4).
// B: [N,K] fp32 — thread t loads row (t>>1), half (t&1): 128B contiguous.
// LDS rows padded to 72 bf16 (144B stride -> 2-way bank alias, free).
// Tile M=256 x N=128, SK=16 (kstot=256 -> ksper=16), 1-deep reg prefetch.
// ---------------------------------------------------------------------------
__global__ __launch_bounds__(256, 2) void gemm_bt64v2_k(
    const __bf16* __restrict__ A, const float* __restrict__ Bm,
    float* __restrict__ Cp, int N, int K, int ksper) {
  __shared__ __bf16 As[256][72];   // 36 KB
  __shared__ __bf16 Bs[128][72];   // 18 KB
  const int tid = threadIdx.x;
  const int bn = blockIdx.x * 128;
  const int lane = tid & 63, wv = tid >> 6;
  const int wr = wv >> 1, wc = wv & 1;
  const int lr = lane & 15, kh = lane >> 4;
  const int brow = tid >> 1, bhalf = tid & 1;
  f32x4 acc[8][4] = {};
  const int kstot = K >> 6;
  int ks0 = blockIdx.z * ksper;
  int ks1 = ks0 + ksper; if (ks1 > kstot) ks1 = kstot;
  uint4 ra[8]; float4 rb[8];
  auto loadT = [&](int ks) {
    const int k0 = ks << 6;
    const uint4* ap = (const uint4*)(A + (size_t)tid * K + k0);
#pragma unroll
    for (int q = 0; q < 8; ++q) ra[q] = ap[q];
    const float* bp = Bm + (size_t)(bn + brow) * K + k0 + bhalf * 32;
#pragma unroll
    for (int q = 0; q < 8; ++q) rb[q] = ((const float4*)bp)[q];
  };
  loadT(ks0);
  for (int ks = ks0; ks < ks1; ++ks) {
    __syncthreads();
#pragma unroll
    for (int q = 0; q < 8; ++q) *(uint4*)&As[tid][q * 8] = ra[q];
#pragma unroll
    for (int q = 0; q < 4; ++q)
      *(bf16x8*)&Bs[brow][bhalf * 32 + q * 8] = cvt8(rb[2 * q], rb[2 * q + 1]);
    __syncthreads();
    if (ks + 1 < ks1) loadT(ks + 1);   // overlaps with MFMA below
#pragma unroll
    for (int kk2 = 0; kk2 < 2; ++kk2) {
      bf16x8 bfv[4];
#pragma unroll
      for (int ni = 0; ni < 4; ++ni)
        bfv[ni] = *(const bf16x8*)&Bs[wc * 64 + ni * 16 + lr][kk2 * 32 + kh * 8];
#pragma unroll
      for (int mi = 0; mi < 8; ++mi) {
        bf16x8 af = *(const bf16x8*)&As[wr * 128 + mi * 16 + lr][kk2 * 32 + kh * 8];
#pragma unroll
        for (int ni = 0; ni < 4; ++ni)
          acc[mi][ni] = __builtin_amdgcn_mfma_f32_16x16x32_bf16(af, bfv[ni],
                                                                acc[mi][ni], 0, 0, 0);
      }
    }
  }
  float* cp = Cp + (size_t)blockIdx.z * 256 * N;
#pragma unroll
  for (int mi = 0; mi < 8; ++mi) {
#pragma unroll
    for (int ni = 0; ni < 4; ++ni) {
      const int row = wr * 128 + mi * 16 + kh * 4;
      const int col = bn + wc * 64 + ni * 16 + lr;
#pragma unroll
      for (int j = 0; j < 4; ++j)
        cp[(size_t)(row + j) * N + col] = acc[mi][ni][j];
    }
  }
}

// ---------------------------------------------------------------------------
// Fused two-layer GRU step, software-pipelined across 33 launches (R10 best).
// ---------------------------------------------------------------------------
__global__ __launch_bounds__(256) void gru_fused2_k(
    const float* __restrict__ X0,      // [256, 3072] layer-0 gi
    const __bf16* __restrict__ Wb0,    // [3072, 1024] bf16 W_hh0
    const float* __restrict__ bhh0,    // [3072]
    float* __restrict__ y0,            // [256, 1024]
    const __bf16* __restrict__ Wbi1,   // [3072, 1024] bf16 W_ih1
    const float* __restrict__ bih1,    // [3072]
    const __bf16* __restrict__ Wbh1,   // [3072, 1024] bf16 W_hh1
    const float* __restrict__ bhh1,    // [3072]
    float* __restrict__ y1,            // [256, 1024]
    int t) {
  __shared__ float sA[8][1024];        // 32 KB
  __shared__ float part[2][2][3][8];   // layer-1 partials [p][role][gate][b]
  const int tid = threadIdx.x;
  const int wv = tid >> 6, lane = tid & 63;

  if (blockIdx.x < 256) {
    // ------------------------- layer 0, step t -------------------------
    if (t >= 32) return;
    const int s = t;
    if (s == 0) {
#pragma unroll
      for (int q = 0; q < 8; ++q) {
        int idx = q * 256 + tid;
        *(float4*)&sA[idx >> 8][(idx & 255) * 4] = make_float4(0.f, 0.f, 0.f, 0.f);
      }
    } else {
#pragma unroll
      for (int q = 0; q < 8; ++q) {
        int idx = q * 256 + tid;
        int b = idx >> 8, kf = (idx & 255) * 4;
        *(float4*)&sA[b][kf] =
            *(const float4*)&y0[(size_t)(b * 32 + s - 1) * 1024 + kf];
      }
    }
    __syncthreads();
    const int j = blockIdx.x * 4 + wv;
    const __bf16* Wr = Wb0 + (size_t)j * 1024;
    const __bf16* Wz = Wb0 + (size_t)(1024 + j) * 1024;
    const __bf16* Wn = Wb0 + (size_t)(2048 + j) * 1024;
    float accR[8] = {}, accZ[8] = {}, accN[8] = {};
#pragma unroll
    for (int kk = 0; kk < 4; ++kk) {
      const int k = kk * 256 + lane * 4;
      uint2 uR = *(const uint2*)&Wr[k];
      uint2 uZ = *(const uint2*)&Wz[k];
      uint2 uN = *(const uint2*)&Wn[k];
      float r0, r1, r2, r3, z0, z1, z2, z3, n0, n1, n2, n3;
      unp2(uR.x, r0, r1); unp2(uR.y, r2, r3);
      unp2(uZ.x, z0, z1); unp2(uZ.y, z2, z3);
      unp2(uN.x, n0, n1); unp2(uN.y, n2, n3);
#pragma unroll
      for (int b = 0; b < 8; ++b) {
        float4 h4 = *(const float4*)&sA[b][k];
        accR[b] += h4.x * r0 + h4.y * r1 + h4.z * r2 + h4.w * r3;
        accZ[b] += h4.x * z0 + h4.y * z1 + h4.z * z2 + h4.w * z3;
        accN[b] += h4.x * n0 + h4.y * n1 + h4.z * n2 + h4.w * n3;
      }
    }
#pragma unroll
    for (int d = 1; d < 64; d <<= 1) {
#pragma unroll
      for (int b = 0; b < 8; ++b) {
        accR[b] += __shfl_xor(accR[b], d);
        accZ[b] += __shfl_xor(accZ[b], d);
        accN[b] += __shfl_xor(accN[b], d);
      }
    }
    if (lane < 8) {
      const int b = lane;
      float sr = 0.f, sz = 0.f, sn = 0.f;
#pragma unroll
      for (int bb = 0; bb < 8; ++bb)
        if (b == bb) { sr = accR[bb]; sz = accZ[bb]; sn = accN[bb]; }
      const float* gip = X0 + (size_t)(b * 32 + s) * 3072;
      float r = 1.0f / (1.0f + __expf(-(gip[j] + sr + bhh0[j])));
      float z = 1.0f / (1.0f + __expf(-(gip[1024 + j] + sz + bhh0[1024 + j])));
      float n = tanhf(gip[2048 + j] + r * (sn + bhh0[2048 + j]));
      float hp = sA[b][j];
      y0[(size_t)(b * 32 + s) * 1024 + j] = (1.0f - z) * n + z * hp;
    }
  } else {
    // ------------------------- layer 1, step t-1 -------------------------
    if (t < 1) return;
    const int s = t - 1;
#pragma unroll
    for (int q = 0; q < 8; ++q) {        // sA = y0[:, s]  (layer-1 input x_t)
      int idx = q * 256 + tid;
      int b = idx >> 8, kf = (idx & 255) * 4;
      *(float4*)&sA[b][kf] =
          *(const float4*)&y0[(size_t)(b * 32 + s) * 1024 + kf];
    }
    __syncthreads();
    const int jb = (int)(blockIdx.x - 256) * 2;
    const int p = wv >> 1, role = wv & 1;
    const int j = jb + p;
    const __bf16* Wm = role ? Wbh1 : Wbi1;
    const __bf16* WR = Wm + (size_t)j * 1024;
    const __bf16* WZ = Wm + (size_t)(1024 + j) * 1024;
    const __bf16* WN = Wm + (size_t)(2048 + j) * 1024;
    float aR[8] = {}, aZ[8] = {}, aN[8] = {};
#pragma unroll
    for (int kk = 0; kk < 4; ++kk) {
      const int k = kk * 256 + lane * 4;
      uint2 uR = *(const uint2*)&WR[k];
      uint2 uZ = *(const uint2*)&WZ[k];
      uint2 uN = *(const uint2*)&WN[k];
      float r0, r1, r2, r3, z0, z1, z2, z3, n0, n1, n2, n3;
      unp2(uR.x, r0, r1); unp2(uR.y, r2, r3);
      unp2(uZ.x, z0, z1); unp2(uZ.y, z2, z3);
      unp2(uN.x, n0, n1); unp2(uN.y, n2, n3);
#pragma unroll
      for (int b = 0; b < 8; ++b) {
        float4 v;
        if (role) {                      // h-side: y1[t-2] direct from L2
          if (s > 0)
            v = *(const float4*)&y1[(size_t)(b * 32 + s - 1) * 1024 + k];
          else
            v = make_float4(0.f, 0.f, 0.f, 0.f);
        } else {
          v = *(const float4*)&sA[b][k];
        }
        aR[b] += v.x * r0 + v.y * r1 + v.z * r2 + v.w * r3;
        aZ[b] += v.x * z0 + v.y * z1 + v.z * z2 + v.w * z3;
        aN[b] += v.x * n0 + v.y * n1 + v.z * n2 + v.w * n3;
      }
    }
#pragma unroll
    for (int d = 1; d < 64; d <<= 1) {
#pragma unroll
      for (int b = 0; b < 8; ++b) {
        aR[b] += __shfl_xor(aR[b], d);
        aZ[b] += __shfl_xor(aZ[b], d);
        aN[b] += __shfl_xor(aN[b], d);
      }
    }
    if (lane == 0) {
#pragma unroll
      for (int b = 0; b < 8; ++b) {
        part[p][role][0][b] = aR[b];
        part[p][role][1][b] = aZ[b];
        part[p][role][2][b] = aN[b];
      }
    }
    __syncthreads();
    if (role == 0 && lane < 8) {
      const int b = lane;
      float xR = part[p][0][0][b], hR = part[p][1][0][b];
      float xZ = part[p][0][1][b], hZ = part[p][1][1][b];
      float xN = part[p][0][2][b], hN = part[p][1][2][b];
      float r = 1.0f / (1.0f + __expf(-(xR + hR + bih1[j] + bhh1[j])));
      float z = 1.0f / (1.0f + __expf(-(xZ + hZ + bih1[1024 + j] + bhh1[1024 + j])));
      float n = tanhf(xN + bih1[2048 + j] + r * (hN + bhh1[2048 + j]));
      float hp = (s > 0) ? y1[(size_t)(b * 32 + s - 1) * 1024 + j] : 0.f;
      y1[(size_t)(b * 32 + s) * 1024 + j] = (1.0f - z) * n + z * hp;
    }
  }
}

// ---------------------------------------------------------------------------
// fp32-input MFMA GEMM (he: B [K,N]) with split-K.
// ---------------------------------------------------------------------------
template <bool BT>
__global__ __launch_bounds__(256) void mfma_gemm_k(const float* __restrict__ A,
                                                   const float* __restrict__ Bm,
                                                   float* __restrict__ Cp,
                                                   int M, int N, int K,
                                                   int lda, int ldb, int ksper) {
  __shared__ __bf16 As[128][40];
  __shared__ __bf16 Bs[128][40];
  const int tid = threadIdx.x;
  const int bm = blockIdx.y * 128, bn = blockIdx.x * 128;
  const int lane = tid & 63, wv = tid >> 6;
  const int wr = wv >> 1, wc = wv & 1;
  const int lr = lane & 15, kh = lane >> 4;
  f32x4 acc[4][4] = {};
  const int kstot = K >> 5;
  int ks0 = blockIdx.z * ksper;
  int ks1 = ks0 + ksper; if (ks1 > kstot) ks1 = kstot;
  for (int ks = ks0; ks < ks1; ++ks) {
    const int k0 = ks << 5;
    __syncthreads();
    {
      const int row = tid >> 1, half = tid & 1;
      const float* ap = A + (size_t)(bm + row) * lda + k0 + half * 16;
      float4 f0 = ((const float4*)ap)[0], f1 = ((const float4*)ap)[1];
      float4 f2 = ((const float4*)ap)[2], f3 = ((const float4*)ap)[3];
      *(bf16x8*)&As[row][half * 16] = cvt8(f0, f1);
      *(bf16x8*)&As[row][half * 16 + 8] = cvt8(f2, f3);
    }
    if (BT) {
      const int row = tid >> 1, half = tid & 1;
      const float* bp = Bm + (size_t)(bn + row) * ldb + k0 + half * 16;
      float4 f0 = ((const float4*)bp)[0], f1 = ((const float4*)bp)[1];
      float4 f2 = ((const float4*)bp)[2], f3 = ((const float4*)bp)[3];
      *(bf16x8*)&Bs[row][half * 16] = cvt8(f0, f1);
      *(bf16x8*)&Bs[row][half * 16 + 8] = cvt8(f2, f3);
    } else {
      const int kk = tid >> 3, ng = tid & 7;
      const float* bp = Bm + (size_t)(k0 + kk) * ldb + bn + ng * 16;
      float4 f[4];
#pragma unroll
      for (int q = 0; q < 4; ++q) f[q] = ((const float4*)bp)[q];
#pragma unroll
      for (int q = 0; q < 4; ++q) {
        Bs[ng * 16 + q * 4 + 0][kk] = (__bf16)f[q].x;
        Bs[ng * 16 + q * 4 + 1][kk] = (__bf16)f[q].y;
        Bs[ng * 16 + q * 4 + 2][kk] = (__bf16)f[q].z;
        Bs[ng * 16 + q * 4 + 3][kk] = (__bf16)f[q].w;
      }
    }
    __syncthreads();
    bf16x8 af[4], bfv[4];
#pragma unroll
    for (int mi = 0; mi < 4; ++mi)
      af[mi] = *(const bf16x8*)&As[wr * 64 + mi * 16 + lr][kh * 8];
#pragma unroll
    for (int ni = 0; ni < 4; ++ni)
      bfv[ni] = *(const bf16x8*)&Bs[wc * 64 + ni * 16 + lr][kh * 8];
#pragma unroll
    for (int mi = 0; mi < 4; ++mi)
#pragma unroll
      for (int ni = 0; ni < 4; ++ni)
        acc[mi][ni] = __builtin_amdgcn_mfma_f32_16x16x32_bf16(af[mi], bfv[ni],
                                                              acc[mi][ni], 0, 0, 0);
  }
  float* cp = Cp + (size_t)blockIdx.z * M * N;
#pragma unroll
  for (int mi = 0; mi < 4; ++mi) {
#pragma unroll
    for (int ni = 0; ni < 4; ++ni) {
      const int row = bm + wr * 64 + mi * 16 + kh * 4;
      const int col = bn + wc * 64 + ni * 16 + lr;
#pragma unroll
      for (int j = 0; j < 4; ++j)
        cp[(size_t)(row + j) * N + col] = acc[mi][ni][j];
    }
  }
}

// C[i] = bias[i%N] + sum_sk Cp[sk][i]
__global__ __launch_bounds__(256) void reduce_k(const float* __restrict__ Cp,
                                                const float* __restrict__ bias,
                                                float* __restrict__ C,
                                                int MN, int N, int nsk) {
  int i = (blockIdx.x * 256 + threadIdx.x) * 4;
  if (i >= MN) return;
  float4 s = make_float4(0.f, 0.f, 0.f, 0.f);
  if (bias) s = *(const float4*)&bias[i % N];
  for (int sk = 0; sk < nsk; ++sk) {
    float4 p = *(const float4*)&Cp[(size_t)sk * MN + i];
    s.x += p.x; s.y += p.y; s.z += p.z; s.w += p.w;
  }
  *(float4*)&C[i] = s;
}

// ---------------------------------------------------------------------------
// h[g,n,c] = he[g,c] + sum_f x_node[g,n,f] * Wg[f,c]   -> stored bf16
// ---------------------------------------------------------------------------
__global__ __launch_bounds__(256) void node_h_k(const float* __restrict__ xn,
                                                const float* __restrict__ Wg,
                                                const float* __restrict__ he,
                                                bf16* __restrict__ hbuf) {
  __shared__ float xns[64][32];
  __shared__ float wgs[32][256];
  const int cq = blockIdx.x, g = blockIdx.y;
  const int tid = threadIdx.x;
  for (int idx = tid; idx < 2048; idx += 256) xns[idx >> 5][idx & 31] = xn[g * 2048 + idx];
  for (int r = 0; r < 32; ++r) wgs[r][tid] = Wg[r * 1024 + cq * 256 + tid];
  __syncthreads();
  const float hev = he[g * 1024 + cq * 256 + tid];
  for (int n0 = 0; n0 < 64; n0 += 8) {
    float acc[8];
#pragma unroll
    for (int nn = 0; nn < 8; ++nn) acc[nn] = hev;
    for (int f = 0; f < 32; ++f) {
      float w = wgs[f][tid];
#pragma unroll
      for (int nn = 0; nn < 8; ++nn) acc[nn] += xns[n0 + nn][f] * w;
    }
#pragma unroll
    for (int nn = 0; nn < 8; ++nn)
      hbuf[(size_t)(g * 64 + n0 + nn) * 1024 + cq * 256 + tid] = __float2bfloat16(acc[nn]);
  }
}

// ---------------------------------------------------------------------------
// a_s[row,hd] = sum_e h[row, hd*256+e] * att_src[hd,e]; same for a_d.
// ---------------------------------------------------------------------------
__global__ __launch_bounds__(256) void as_ad_k(const bf16* __restrict__ hbuf,
                                               const float* __restrict__ att_s,
                                               const float* __restrict__ att_d,
                                               float* __restrict__ as_o,
                                               float* __restrict__ ad_o) {
  const int tid = threadIdx.x;
  const int lane = tid & 63, wv = tid >> 6;
  const int row = blockIdx.x * 4 + wv;
  const int hd = lane >> 4;
  const int e0 = (lane & 15) * 16;
  float as_r[16], ad_r[16];
#pragma unroll
  for (int q = 0; q < 4; ++q) {
    float4 v = *(const float4*)(att_s + hd * 256 + e0 + q * 4);
    as_r[q * 4 + 0] = v.x; as_r[q * 4 + 1] = v.y; as_r[q * 4 + 2] = v.z; as_r[q * 4 + 3] = v.w;
    float4 w = *(const float4*)(att_d + hd * 256 + e0 + q * 4);
    ad_r[q * 4 + 0] = w.x; ad_r[q * 4 + 1] = w.y; ad_r[q * 4 + 2] = w.z; ad_r[q * 4 + 3] = w.w;
  }
  const uint4* hp = (const uint4*)(hbuf + (size_t)row * 1024 + lane * 16);
  uint4 p0 = hp[0], p1 = hp[1];
  float hv[16];
  unp2(p0.x, hv[0], hv[1]);  unp2(p0.y, hv[2], hv[3]);
  unp2(p0.z, hv[4], hv[5]);  unp2(p0.w, hv[6], hv[7]);
  unp2(p1.x, hv[8], hv[9]);  unp2(p1.y, hv[10], hv[11]);
  unp2(p1.z, hv[12], hv[13]); unp2(p1.w, hv[14], hv[15]);
  float ps = 0.f, pd = 0.f;
#pragma unroll
  for (int i = 0; i < 16; ++i) { ps += as_r[i] * hv[i]; pd += ad_r[i] * hv[i]; }
#pragma unroll
  for (int m = 1; m < 16; m <<= 1) { ps += __shfl_xor(ps, m); pd += __shfl_xor(pd, m); }
  if ((lane & 15) == 0) { as_o[row * 4 + hd] = ps; ad_o[row * 4 + hd] = pd; }
}

// ---------------------------------------------------------------------------
// Per graph g: softmax over sources + head-mean aggregation + bias + relu.
// ---------------------------------------------------------------------------
__global__ __launch_bounds__(256) void attn_agg_k(const bf16* __restrict__ hbuf,
                                                  const float* __restrict__ as_i,
                                                  const float* __restrict__ ad_i,
                                                  const float* __restrict__ bgat,
                                                  __bf16* __restrict__ seq) {
  __shared__ float ass[256], ads[256], bgs[256];
  __shared__ float alpha[4][64][64];   // [hd][j][i]
  __shared__ float hq[64][260];        // one head-quarter of h, fp32
  const int g = blockIdx.x, tid = threadIdx.x;
  ass[tid] = as_i[g * 256 + tid];
  ads[tid] = ad_i[g * 256 + tid];
  bgs[tid] = bgat[tid];
  __syncthreads();
  {
    const int hd = tid >> 6, i = tid & 63;
    const float ad = ads[i * 4 + hd];
    float m = -1e30f;
    for (int j = 0; j < 64; ++j) {
      float s = ad + ass[j * 4 + hd];
      s = s > 0.0f ? s : 0.2f * s;
      m = fmaxf(m, s);
    }
    float sum = 0.0f;
    for (int j = 0; j < 64; ++j) {
      float s = ad + ass[j * 4 + hd];
      s = s > 0.0f ? s : 0.2f * s;
      sum += __expf(s - m);
    }
    const float inv = 1.0f / sum;
    for (int j = 0; j < 64; ++j) {
      float s = ad + ass[j * 4 + hd];
      s = s > 0.0f ? s : 0.2f * s;
      alpha[hd][j][i] = __expf(s - m) * inv;
    }
  }
  const int i = tid & 63, eq = tid >> 6;
  float acc[64] = {};
  for (int hd = 0; hd < 4; ++hd) {
    __syncthreads();
    for (int idx = tid; idx < 2048; idx += 256) {
      int j = idx >> 5, ch = idx & 31;
      uint4 p = *(const uint4*)(hbuf + (size_t)(g * 64 + j) * 1024 + hd * 256 + ch * 8);
      float f0, f1, f2, f3, f4, f5, f6, f7;
      unp2(p.x, f0, f1); unp2(p.y, f2, f3); unp2(p.z, f4, f5); unp2(p.w, f6, f7);
      *(float4*)&hq[j][ch * 8] = make_float4(f0, f1, f2, f3);
      *(float4*)&hq[j][ch * 8 + 4] = make_float4(f4, f5, f6, f7);
    }
    __syncthreads();
    for (int j = 0; j < 64; ++j) {
      const float a = alpha[hd][j][i];
      const float* hr = &hq[j][eq * 64];
#pragma unroll
      for (int q = 0; q < 16; ++q) {
        float4 hv = *(const float4*)(hr + q * 4);
        acc[q * 4 + 0] += a * hv.x; acc[q * 4 + 1] += a * hv.y;
        acc[q * 4 + 2] += a * hv.z; acc[q * 4 + 3] += a * hv.w;
      }
    }
  }
  __bf16* op = seq + (size_t)g * 16384 + i * 256 + eq * 64;
#pragma unroll
  for (int q = 0; q < 8; ++q) {
    float4 lo, hi;
    lo.x = fmaxf(bgs[eq * 64 + q * 8 + 0] + 0.25f * acc[q * 8 + 0], 0.0f);
    lo.y = fmaxf(bgs[eq * 64 + q * 8 + 1] + 0.25f * acc[q * 8 + 1], 0.0f);
    lo.z = fmaxf(bgs[eq * 64 + q * 8 + 2] + 0.25f * acc[q * 8 + 2], 0.0f);
    lo.w = fmaxf(bgs[eq * 64 + q * 8 + 3] + 0.25f * acc[q * 8 + 3], 0.0f);
    hi.x = fmaxf(bgs[eq * 64 + q * 8 + 4] + 0.25f * acc[q * 8 + 4], 0.0f);
    hi.y = fmaxf(bgs[eq * 64 + q * 8 + 5] + 0.25f * acc[q * 8 + 5], 0.0f);
    hi.z = fmaxf(bgs[eq * 64 + q * 8 + 6] + 0.25f * acc[q * 8 + 6], 0.0f);
    hi.w = fmaxf(bgs[eq * 64 + q * 8 + 7] + 0.25f * acc[q * 8 + 7], 0.0f);
    *(bf16x8*)(op + q * 8) = cvt8(lo, hi);
  }
}

// ---------------------------------------------------------------------------
// out[b,o] = b_fc[o] + sum_k y1[b,31,k] * Wfc[k,o]
// ---------------------------------------------------------------------------
__global__ __launch_bounds__(256) void fc_k(const float* __restrict__ y1,
                                            const float* __restrict__ Wfc,
                                            const float* __restrict__ bfc,
                                            float* __restrict__ out) {
  __shared__ float As[8][1024];
  const int tid = threadIdx.x;
  for (int idx = tid; idx < 8192; idx += 256) {
    int b = idx >> 10, k = idx & 1023;
    As[b][k] = y1[(size_t)(b * 32 + 31) * 1024 + k];
  }
  __syncthreads();
  const int ol = tid >> 2, kq = tid & 3;
  const int o = blockIdx.x * 64 + ol;
  float acc[8] = {};
  if (o < 2016) {
    for (int i2 = 0; i2 < 256; ++i2) {
      int k = i2 * 4 + kq;
      float w = Wfc[(size_t)k * 2016 + o];
#pragma unroll
      for (int b = 0; b < 8; ++b) acc[b] += As[b][k] * w;
    }
  }
#pragma unroll
  for (int b = 0; b < 8; ++b) {
    acc[b] += __shfl_xor(acc[b], 1);
    acc[b] += __shfl_xor(acc[b], 2);
  }
  if (kq == 0 && o < 2016) {
#pragma unroll
    for (int b = 0; b < 8; ++b) out[b * 2016 + o] = acc[b] + bfc[o];
  }
}

// ---------------------------------------------------------------------------
extern "C" void kernel_launch(void* const* d_in, const int* in_sizes, int n_in,
                              void* d_out, int out_size, void* d_ws, size_t ws_size,
                              hipStream_t stream) {
  (void)in_sizes; (void)n_in; (void)out_size; (void)ws_size;
  const float* x_node = (const float*)d_in[0];
  const float* x_edge = (const float*)d_in[1];
  // d_in[2] = edge_index: complete graph + self loops -> dense; unused.
  const float* W_gat = (const float*)d_in[3];
  const float* att_s = (const float*)d_in[4];
  const float* att_d = (const float*)d_in[5];
  const float* b_gat = (const float*)d_in[6];
  const float* W_ih0 = (const float*)d_in[7];
  const float* W_hh0 = (const float*)d_in[8];
  const float* b_ih0 = (const float*)d_in[9];
  const float* b_hh0 = (const float*)d_in[10];
  const float* W_ih1 = (const float*)d_in[11];
  const float* W_hh1 = (const float*)d_in[12];
  const float* b_ih1 = (const float*)d_in[13];
  const float* b_hh1 = (const float*)d_in[14];
  const float* W_fc  = (const float*)d_in[15];
  const float* b_fc  = (const float*)d_in[16];

  char* ws = (char*)d_ws;
  size_t off = 0;
  float*  he   = (float*)(ws + off);   off += 256u * 1024 * 4;          // 1 MB
  float*  a_s  = (float*)(ws + off);   off += 256u * 64 * 4 * 4;        // 256 KB
  float*  a_d  = (float*)(ws + off);   off += 256u * 64 * 4 * 4;        // 256 KB
  bf16*   hb   = (bf16*)(ws + off);    off += 256u * 64 * 1024 * 2;     // 32 MB
  __bf16* seq  = (__bf16*)(ws + off);  off += 256u * 16384 * 2;         // 8 MB
  float*  X0   = (float*)(ws + off);   off += 256u * 3072 * 4;          // 3 MB
  float*  y0   = (float*)(ws + off);   off += 256u * 1024 * 4;          // 1 MB
  float*  y1   = (float*)(ws + off);   off += 256u * 1024 * 4;          // 1 MB
  __bf16* Wb0  = (__bf16*)(ws + off);  off += 3072u * 1024 * 2;         // 6 MB
  __bf16* Wbi1 = (__bf16*)(ws + off);  off += 3072u * 1024 * 2;         // 6 MB
  __bf16* Wbh1 = (__bf16*)(ws + off);  off += 3072u * 1024 * 2;         // 6 MB
  off = (off + 255) & ~(size_t)255;
  float*  Cp   = (float*)(ws + off);   off += (size_t)16 * 256 * 3072 * 4; // 48 MB

  // 0) bf16 copies of RNN weights (once per call; L2-resident thereafter)
  wcvt_k<<<1536, 256, 0, stream>>>(W_hh0, W_ih1, W_hh1, Wb0, Wbi1, Wbh1);
  // 1) he = x_edge @ W_gat[32:, :]   (M=256, N=1024, K=2016, B is [K,N]) SK=8
  mfma_gemm_k<false><<<dim3(8, 2, 8), 256, 0, stream>>>(
      x_edge, W_gat + 32 * 1024, Cp, 256, 1024, 2016, 2016, 1024, 8);
  reduce_k<<<256, 256, 0, stream>>>(Cp, nullptr, he, 256 * 1024, 1024, 8);
  // 2) h = node-proj + he (bf16)
  node_h_k<<<dim3(4, 256), 256, 0, stream>>>(x_node, W_gat, he, hb);
  // 3) attention logits
  as_ad_k<<<4096, 256, 0, stream>>>(hb, att_s, att_d, a_s, a_d);
  // 4) softmax + aggregation + relu -> seq [256, 16384] bf16
  attn_agg_k<<<256, 256, 0, stream>>>(hb, a_s, a_d, b_gat, seq);
  // 5) X0 = seq @ W_ih0^T + b_ih0   (M=256, N=3072, K=16384) BK=64, SK=16,
  //    launch_bounds(256,2) -> 256-VGPR budget, no spill (R12's failure mode)
  gemm_bt64v2_k<<<dim3(24, 1, 16), 256, 0, stream>>>(seq, W_ih0, Cp,
                                                     3072, 16384, 16);
  reduce_k<<<768, 256, 0, stream>>>(Cp, b_ih0, X0, 256 * 3072, 3072, 16);
  // 6) Both GRU layers, software-pipelined (R10 best): launch t = layer0
  //    step t (256 blocks) + layer1 step t-1 (512 blocks, fused input proj).
  for (int t = 0; t <= 32; ++t)
    gru_fused2_k<<<768, 256, 0, stream>>>(X0, Wb0, b_hh0, y0,
                                          Wbi1, b_ih1, Wbh1, b_hh1, y1, t);
  // 7) out = y1[:, 31] @ W_fc + b_fc
  fc_k<<<32, 256, 0, stream>>>(y1, W_fc, b_fc, (float*)d_out);
}

// Round 15
// 655.107 us; speedup vs baseline: 1.1059x; 1.1059x over previous
//
#include <hip/hip_runtime.h>
#include <hip/hip_bf16.h>

using bf16 = __hip_bfloat16;
typedef __bf16 bf16x8 __attribute__((ext_vector_type(8)));
typedef float f32x4 __attribute__((ext_vector_type(4)));

// Sizes (fixed): B=8 S=32 N=64 F_NODE=32 TRI=2016 DIN=2048 H=4 DOUT=256 R=1024
// OUT=2016, G=B*S=256 graphs

__device__ __forceinline__ void unp2(unsigned int u, float& a, float& b) {
  a = __uint_as_float(u << 16);
  b = __uint_as_float(u & 0xffff0000u);
}

__device__ __forceinline__ bf16x8 cvt8(float4 a, float4 b) {
  bf16x8 r;
  r[0] = (__bf16)a.x; r[1] = (__bf16)a.y; r[2] = (__bf16)a.z; r[3] = (__bf16)a.w;
  r[4] = (__bf16)b.x; r[5] = (__bf16)b.y; r[6] = (__bf16)b.z; r[7] = (__bf16)b.w;
  return r;
}

// ---------------------------------------------------------------------------
// One-shot fp32 -> bf16 conversion of the three RNN weight matrices.
// ---------------------------------------------------------------------------
__global__ __launch_bounds__(256) void wcvt_k(const float* __restrict__ a,
                                              const float* __restrict__ b,
                                              const float* __restrict__ c,
                                              __bf16* __restrict__ A,
                                              __bf16* __restrict__ B,
                                              __bf16* __restrict__ C) {
  const int i = (blockIdx.x * 256 + threadIdx.x) * 8;
  float4 x0 = *(const float4*)&a[i], x1 = *(const float4*)&a[i + 4];
  *(bf16x8*)&A[i] = cvt8(x0, x1);
  float4 y0_ = *(const float4*)&b[i], y1_ = *(const float4*)&b[i + 4];
  *(bf16x8*)&B[i] = cvt8(y0_, y1_);
  float4 z0 = *(const float4*)&c[i], z1 = *(const float4*)&c[i + 4];
  *(bf16x8*)&C[i] = cvt8(z0, z1);
}

// ---------------------------------------------------------------------------
// X0 GEMM, BK=64, prefetch in NAMED scalar registers (no arrays -> no
// scratch; R12/R13's ra[8]/rb[8] arrays were compiled to localMem, 136 MB
// of scratch writes per dispatch — rule: never runtime-index prefetch regs).
// A: [256,K] bf16 — thread t loads row t's 128B chunk.
// B: [N,K] fp32 — thread t loads row (t>>1), half (t&1): 128B contiguous.
// LDS rows padded to 72 bf16 (144B stride -> 2-way bank alias, free).
// Tile M=256 x N=128, SK=16, launch_bounds(256,2) = 256-VGPR budget.
// ---------------------------------------------------------------------------
__global__ __launch_bounds__(256, 2) void gemm_bt64v3_k(
    const __bf16* __restrict__ A, const float* __restrict__ Bm,
    float* __restrict__ Cp, int N, int K, int ksper) {
  __shared__ __bf16 As[256][72];   // 36 KB
  __shared__ __bf16 Bs[128][72];   // 18 KB
  const int tid = threadIdx.x;
  const int bn = blockIdx.x * 128;
  const int lane = tid & 63, wv = tid >> 6;
  const int wr = wv >> 1, wc = wv & 1;
  const int lr = lane & 15, kh = lane >> 4;
  const int brow = tid >> 1, bhalf = tid & 1;
  f32x4 acc[8][4] = {};
  const int kstot = K >> 6;
  int ks0 = blockIdx.z * ksper;
  int ks1 = ks0 + ksper; if (ks1 > kstot) ks1 = kstot;
  uint4 a0, a1, a2, a3, a4, a5, a6, a7;
  float4 b0, b1, b2, b3, b4, b5, b6, b7;
#define LOADT(ksv)                                                        \
  {                                                                       \
    const int k0_ = (ksv) << 6;                                           \
    const uint4* ap_ = (const uint4*)(A + (size_t)tid * K + k0_);         \
    a0 = ap_[0]; a1 = ap_[1]; a2 = ap_[2]; a3 = ap_[3];                   \
    a4 = ap_[4]; a5 = ap_[5]; a6 = ap_[6]; a7 = ap_[7];                   \
    const float4* bp_ = (const float4*)(Bm + (size_t)(bn + brow) * K +    \
                                        k0_ + bhalf * 32);                \
    b0 = bp_[0]; b1 = bp_[1]; b2 = bp_[2]; b3 = bp_[3];                   \
    b4 = bp_[4]; b5 = bp_[5]; b6 = bp_[6]; b7 = bp_[7];                   \
  }
  LOADT(ks0);
  for (int ks = ks0; ks < ks1; ++ks) {
    __syncthreads();
    *(uint4*)&As[tid][0]  = a0; *(uint4*)&As[tid][8]  = a1;
    *(uint4*)&As[tid][16] = a2; *(uint4*)&As[tid][24] = a3;
    *(uint4*)&As[tid][32] = a4; *(uint4*)&As[tid][40] = a5;
    *(uint4*)&As[tid][48] = a6; *(uint4*)&As[tid][56] = a7;
    *(bf16x8*)&Bs[brow][bhalf * 32]      = cvt8(b0, b1);
    *(bf16x8*)&Bs[brow][bhalf * 32 + 8]  = cvt8(b2, b3);
    *(bf16x8*)&Bs[brow][bhalf * 32 + 16] = cvt8(b4, b5);
    *(bf16x8*)&Bs[brow][bhalf * 32 + 24] = cvt8(b6, b7);
    __syncthreads();
    if (ks + 1 < ks1) LOADT(ks + 1);   // overlaps with MFMA below
#pragma unroll
    for (int kk2 = 0; kk2 < 2; ++kk2) {
      bf16x8 bfv[4];
#pragma unroll
      for (int ni = 0; ni < 4; ++ni)
        bfv[ni] = *(const bf16x8*)&Bs[wc * 64 + ni * 16 + lr][kk2 * 32 + kh * 8];
#pragma unroll
      for (int mi = 0; mi < 8; ++mi) {
        bf16x8 af = *(const bf16x8*)&As[wr * 128 + mi * 16 + lr][kk2 * 32 + kh * 8];
#pragma unroll
        for (int ni = 0; ni < 4; ++ni)
          acc[mi][ni] = __builtin_amdgcn_mfma_f32_16x16x32_bf16(af, bfv[ni],
                                                                acc[mi][ni], 0, 0, 0);
      }
    }
  }
#undef LOADT
  float* cp = Cp + (size_t)blockIdx.z * 256 * N;
#pragma unroll
  for (int mi = 0; mi < 8; ++mi) {
#pragma unroll
    for (int ni = 0; ni < 4; ++ni) {
      const int row = wr * 128 + mi * 16 + kh * 4;
      const int col = bn + wc * 64 + ni * 16 + lr;
#pragma unroll
      for (int j = 0; j < 4; ++j)
        cp[(size_t)(row + j) * N + col] = acc[mi][ni][j];
    }
  }
}

// ---------------------------------------------------------------------------
// Fused two-layer GRU step, software-pipelined across 33 launches (R10 best).
// ---------------------------------------------------------------------------
__global__ __launch_bounds__(256) void gru_fused2_k(
    const float* __restrict__ X0,      // [256, 3072] layer-0 gi
    const __bf16* __restrict__ Wb0,    // [3072, 1024] bf16 W_hh0
    const float* __restrict__ bhh0,    // [3072]
    float* __restrict__ y0,            // [256, 1024]
    const __bf16* __restrict__ Wbi1,   // [3072, 1024] bf16 W_ih1
    const float* __restrict__ bih1,    // [3072]
    const __bf16* __restrict__ Wbh1,   // [3072, 1024] bf16 W_hh1
    const float* __restrict__ bhh1,    // [3072]
    float* __restrict__ y1,            // [256, 1024]
    int t) {
  __shared__ float sA[8][1024];        // 32 KB
  __shared__ float part[2][2][3][8];   // layer-1 partials [p][role][gate][b]
  const int tid = threadIdx.x;
  const int wv = tid >> 6, lane = tid & 63;

  if (blockIdx.x < 256) {
    // ------------------------- layer 0, step t -------------------------
    if (t >= 32) return;
    const int s = t;
    if (s == 0) {
#pragma unroll
      for (int q = 0; q < 8; ++q) {
        int idx = q * 256 + tid;
        *(float4*)&sA[idx >> 8][(idx & 255) * 4] = make_float4(0.f, 0.f, 0.f, 0.f);
      }
    } else {
#pragma unroll
      for (int q = 0; q < 8; ++q) {
        int idx = q * 256 + tid;
        int b = idx >> 8, kf = (idx & 255) * 4;
        *(float4*)&sA[b][kf] =
            *(const float4*)&y0[(size_t)(b * 32 + s - 1) * 1024 + kf];
      }
    }
    __syncthreads();
    const int j = blockIdx.x * 4 + wv;
    const __bf16* Wr = Wb0 + (size_t)j * 1024;
    const __bf16* Wz = Wb0 + (size_t)(1024 + j) * 1024;
    const __bf16* Wn = Wb0 + (size_t)(2048 + j) * 1024;
    float accR[8] = {}, accZ[8] = {}, accN[8] = {};
#pragma unroll
    for (int kk = 0; kk < 4; ++kk) {
      const int k = kk * 256 + lane * 4;
      uint2 uR = *(const uint2*)&Wr[k];
      uint2 uZ = *(const uint2*)&Wz[k];
      uint2 uN = *(const uint2*)&Wn[k];
      float r0, r1, r2, r3, z0, z1, z2, z3, n0, n1, n2, n3;
      unp2(uR.x, r0, r1); unp2(uR.y, r2, r3);
      unp2(uZ.x, z0, z1); unp2(uZ.y, z2, z3);
      unp2(uN.x, n0, n1); unp2(uN.y, n2, n3);
#pragma unroll
      for (int b = 0; b < 8; ++b) {
        float4 h4 = *(const float4*)&sA[b][k];
        accR[b] += h4.x * r0 + h4.y * r1 + h4.z * r2 + h4.w * r3;
        accZ[b] += h4.x * z0 + h4.y * z1 + h4.z * z2 + h4.w * z3;
        accN[b] += h4.x * n0 + h4.y * n1 + h4.z * n2 + h4.w * n3;
      }
    }
#pragma unroll
    for (int d = 1; d < 64; d <<= 1) {
#pragma unroll
      for (int b = 0; b < 8; ++b) {
        accR[b] += __shfl_xor(accR[b], d);
        accZ[b] += __shfl_xor(accZ[b], d);
        accN[b] += __shfl_xor(accN[b], d);
      }
    }
    if (lane < 8) {
      const int b = lane;
      float sr = 0.f, sz = 0.f, sn = 0.f;
#pragma unroll
      for (int bb = 0; bb < 8; ++bb)
        if (b == bb) { sr = accR[bb]; sz = accZ[bb]; sn = accN[bb]; }
      const float* gip = X0 + (size_t)(b * 32 + s) * 3072;
      float r = 1.0f / (1.0f + __expf(-(gip[j] + sr + bhh0[j])));
      float z = 1.0f / (1.0f + __expf(-(gip[1024 + j] + sz + bhh0[1024 + j])));
      float n = tanhf(gip[2048 + j] + r * (sn + bhh0[2048 + j]));
      float hp = sA[b][j];
      y0[(size_t)(b * 32 + s) * 1024 + j] = (1.0f - z) * n + z * hp;
    }
  } else {
    // ------------------------- layer 1, step t-1 -------------------------
    if (t < 1) return;
    const int s = t - 1;
#pragma unroll
    for (int q = 0; q < 8; ++q) {        // sA = y0[:, s]  (layer-1 input x_t)
      int idx = q * 256 + tid;
      int b = idx >> 8, kf = (idx & 255) * 4;
      *(float4*)&sA[b][kf] =
          *(const float4*)&y0[(size_t)(b * 32 + s) * 1024 + kf];
    }
    __syncthreads();
    const int jb = (int)(blockIdx.x - 256) * 2;
    const int p = wv >> 1, role = wv & 1;
    const int j = jb + p;
    const __bf16* Wm = role ? Wbh1 : Wbi1;
    const __bf16* WR = Wm + (size_t)j * 1024;
    const __bf16* WZ = Wm + (size_t)(1024 + j) * 1024;
    const __bf16* WN = Wm + (size_t)(2048 + j) * 1024;
    float aR[8] = {}, aZ[8] = {}, aN[8] = {};
#pragma unroll
    for (int kk = 0; kk < 4; ++kk) {
      const int k = kk * 256 + lane * 4;
      uint2 uR = *(const uint2*)&WR[k];
      uint2 uZ = *(const uint2*)&WZ[k];
      uint2 uN = *(const uint2*)&WN[k];
      float r0, r1, r2, r3, z0, z1, z2, z3, n0, n1, n2, n3;
      unp2(uR.x, r0, r1); unp2(uR.y, r2, r3);
      unp2(uZ.x, z0, z1); unp2(uZ.y, z2, z3);
      unp2(uN.x, n0, n1); unp2(uN.y, n2, n3);
#pragma unroll
      for (int b = 0; b < 8; ++b) {
        float4 v;
        if (role) {                      // h-side: y1[t-2] direct from L2
          if (s > 0)
            v = *(const float4*)&y1[(size_t)(b * 32 + s - 1) * 1024 + k];
          else
            v = make_float4(0.f, 0.f, 0.f, 0.f);
        } else {
          v = *(const float4*)&sA[b][k];
        }
        aR[b] += v.x * r0 + v.y * r1 + v.z * r2 + v.w * r3;
        aZ[b] += v.x * z0 + v.y * z1 + v.z * z2 + v.w * z3;
        aN[b] += v.x * n0 + v.y * n1 + v.z * n2 + v.w * n3;
      }
    }
#pragma unroll
    for (int d = 1; d < 64; d <<= 1) {
#pragma unroll
      for (int b = 0; b < 8; ++b) {
        aR[b] += __shfl_xor(aR[b], d);
        aZ[b] += __shfl_xor(aZ[b], d);
        aN[b] += __shfl_xor(aN[b], d);
      }
    }
    if (lane == 0) {
#pragma unroll
      for (int b = 0; b < 8; ++b) {
        part[p][role][0][b] = aR[b];
        part[p][role][1][b] = aZ[b];
        part[p][role][2][b] = aN[b];
      }
    }
    __syncthreads();
    if (role == 0 && lane < 8) {
      const int b = lane;
      float xR = part[p][0][0][b], hR = part[p][1][0][b];
      float xZ = part[p][0][1][b], hZ = part[p][1][1][b];
      float xN = part[p][0][2][b], hN = part[p][1][2][b];
      float r = 1.0f / (1.0f + __expf(-(xR + hR + bih1[j] + bhh1[j])));
      float z = 1.0f / (1.0f + __expf(-(xZ + hZ + bih1[1024 + j] + bhh1[1024 + j])));
      float n = tanhf(xN + bih1[2048 + j] + r * (hN + bhh1[2048 + j]));
      float hp = (s > 0) ? y1[(size_t)(b * 32 + s - 1) * 1024 + j] : 0.f;
      y1[(size_t)(b * 32 + s) * 1024 + j] = (1.0f - z) * n + z * hp;
    }
  }
}

// ---------------------------------------------------------------------------
// fp32-input MFMA GEMM (he: B [K,N]) with split-K.
// ---------------------------------------------------------------------------
template <bool BT>
__global__ __launch_bounds__(256) void mfma_gemm_k(const float* __restrict__ A,
                                                   const float* __restrict__ Bm,
                                                   float* __restrict__ Cp,
                                                   int M, int N, int K,
                                                   int lda, int ldb, int ksper) {
  __shared__ __bf16 As[128][40];
  __shared__ __bf16 Bs[128][40];
  const int tid = threadIdx.x;
  const int bm = blockIdx.y * 128, bn = blockIdx.x * 128;
  const int lane = tid & 63, wv = tid >> 6;
  const int wr = wv >> 1, wc = wv & 1;
  const int lr = lane & 15, kh = lane >> 4;
  f32x4 acc[4][4] = {};
  const int kstot = K >> 5;
  int ks0 = blockIdx.z * ksper;
  int ks1 = ks0 + ksper; if (ks1 > kstot) ks1 = kstot;
  for (int ks = ks0; ks < ks1; ++ks) {
    const int k0 = ks << 5;
    __syncthreads();
    {
      const int row = tid >> 1, half = tid & 1;
      const float* ap = A + (size_t)(bm + row) * lda + k0 + half * 16;
      float4 f0 = ((const float4*)ap)[0], f1 = ((const float4*)ap)[1];
      float4 f2 = ((const float4*)ap)[2], f3 = ((const float4*)ap)[3];
      *(bf16x8*)&As[row][half * 16] = cvt8(f0, f1);
      *(bf16x8*)&As[row][half * 16 + 8] = cvt8(f2, f3);
    }
    if (BT) {
      const int row = tid >> 1, half = tid & 1;
      const float* bp = Bm + (size_t)(bn + row) * ldb + k0 + half * 16;
      float4 f0 = ((const float4*)bp)[0], f1 = ((const float4*)bp)[1];
      float4 f2 = ((const float4*)bp)[2], f3 = ((const float4*)bp)[3];
      *(bf16x8*)&Bs[row][half * 16] = cvt8(f0, f1);
      *(bf16x8*)&Bs[row][half * 16 + 8] = cvt8(f2, f3);
    } else {
      const int kk = tid >> 3, ng = tid & 7;
      const float* bp = Bm + (size_t)(k0 + kk) * ldb + bn + ng * 16;
      float4 f[4];
#pragma unroll
      for (int q = 0; q < 4; ++q) f[q] = ((const float4*)bp)[q];
#pragma unroll
      for (int q = 0; q < 4; ++q) {
        Bs[ng * 16 + q * 4 + 0][kk] = (__bf16)f[q].x;
        Bs[ng * 16 + q * 4 + 1][kk] = (__bf16)f[q].y;
        Bs[ng * 16 + q * 4 + 2][kk] = (__bf16)f[q].z;
        Bs[ng * 16 + q * 4 + 3][kk] = (__bf16)f[q].w;
      }
    }
    __syncthreads();
    bf16x8 af[4], bfv[4];
#pragma unroll
    for (int mi = 0; mi < 4; ++mi)
      af[mi] = *(const bf16x8*)&As[wr * 64 + mi * 16 + lr][kh * 8];
#pragma unroll
    for (int ni = 0; ni < 4; ++ni)
      bfv[ni] = *(const bf16x8*)&Bs[wc * 64 + ni * 16 + lr][kh * 8];
#pragma unroll
    for (int mi = 0; mi < 4; ++mi)
#pragma unroll
      for (int ni = 0; ni < 4; ++ni)
        acc[mi][ni] = __builtin_amdgcn_mfma_f32_16x16x32_bf16(af[mi], bfv[ni],
                                                              acc[mi][ni], 0, 0, 0);
  }
  float* cp = Cp + (size_t)blockIdx.z * M * N;
#pragma unroll
  for (int mi = 0; mi < 4; ++mi) {
#pragma unroll
    for (int ni = 0; ni < 4; ++ni) {
      const int row = bm + wr * 64 + mi * 16 + kh * 4;
      const int col = bn + wc * 64 + ni * 16 + lr;
#pragma unroll
      for (int j = 0; j < 4; ++j)
        cp[(size_t)(row + j) * N + col] = acc[mi][ni][j];
    }
  }
}

// C[i] = bias[i%N] + sum_sk Cp[sk][i]
__global__ __launch_bounds__(256) void reduce_k(const float* __restrict__ Cp,
                                                const float* __restrict__ bias,
                                                float* __restrict__ C,
                                                int MN, int N, int nsk) {
  int i = (blockIdx.x * 256 + threadIdx.x) * 4;
  if (i >= MN) return;
  float4 s = make_float4(0.f, 0.f, 0.f, 0.f);
  if (bias) s = *(const float4*)&bias[i % N];
  for (int sk = 0; sk < nsk; ++sk) {
    float4 p = *(const float4*)&Cp[(size_t)sk * MN + i];
    s.x += p.x; s.y += p.y; s.z += p.z; s.w += p.w;
  }
  *(float4*)&C[i] = s;
}

// ---------------------------------------------------------------------------
// h[g,n,c] = he[g,c] + sum_f x_node[g,n,f] * Wg[f,c]   -> stored bf16
// ---------------------------------------------------------------------------
__global__ __launch_bounds__(256) void node_h_k(const float* __restrict__ xn,
                                                const float* __restrict__ Wg,
                                                const float* __restrict__ he,
                                                bf16* __restrict__ hbuf) {
  __shared__ float xns[64][32];
  __shared__ float wgs[32][256];
  const int cq = blockIdx.x, g = blockIdx.y;
  const int tid = threadIdx.x;
  for (int idx = tid; idx < 2048; idx += 256) xns[idx >> 5][idx & 31] = xn[g * 2048 + idx];
  for (int r = 0; r < 32; ++r) wgs[r][tid] = Wg[r * 1024 + cq * 256 + tid];
  __syncthreads();
  const float hev = he[g * 1024 + cq * 256 + tid];
  for (int n0 = 0; n0 < 64; n0 += 8) {
    float acc[8];
#pragma unroll
    for (int nn = 0; nn < 8; ++nn) acc[nn] = hev;
    for (int f = 0; f < 32; ++f) {
      float w = wgs[f][tid];
#pragma unroll
      for (int nn = 0; nn < 8; ++nn) acc[nn] += xns[n0 + nn][f] * w;
    }
#pragma unroll
    for (int nn = 0; nn < 8; ++nn)
      hbuf[(size_t)(g * 64 + n0 + nn) * 1024 + cq * 256 + tid] = __float2bfloat16(acc[nn]);
  }
}

// ---------------------------------------------------------------------------
// a_s[row,hd] = sum_e h[row, hd*256+e] * att_src[hd,e]; same for a_d.
// ---------------------------------------------------------------------------
__global__ __launch_bounds__(256) void as_ad_k(const bf16* __restrict__ hbuf,
                                               const float* __restrict__ att_s,
                                               const float* __restrict__ att_d,
                                               float* __restrict__ as_o,
                                               float* __restrict__ ad_o) {
  const int tid = threadIdx.x;
  const int lane = tid & 63, wv = tid >> 6;
  const int row = blockIdx.x * 4 + wv;
  const int hd = lane >> 4;
  const int e0 = (lane & 15) * 16;
  float as_r[16], ad_r[16];
#pragma unroll
  for (int q = 0; q < 4; ++q) {
    float4 v = *(const float4*)(att_s + hd * 256 + e0 + q * 4);
    as_r[q * 4 + 0] = v.x; as_r[q * 4 + 1] = v.y; as_r[q * 4 + 2] = v.z; as_r[q * 4 + 3] = v.w;
    float4 w = *(const float4*)(att_d + hd * 256 + e0 + q * 4);
    ad_r[q * 4 + 0] = w.x; ad_r[q * 4 + 1] = w.y; ad_r[q * 4 + 2] = w.z; ad_r[q * 4 + 3] = w.w;
  }
  const uint4* hp = (const uint4*)(hbuf + (size_t)row * 1024 + lane * 16);
  uint4 p0 = hp[0], p1 = hp[1];
  float hv[16];
  unp2(p0.x, hv[0], hv[1]);  unp2(p0.y, hv[2], hv[3]);
  unp2(p0.z, hv[4], hv[5]);  unp2(p0.w, hv[6], hv[7]);
  unp2(p1.x, hv[8], hv[9]);  unp2(p1.y, hv[10], hv[11]);
  unp2(p1.z, hv[12], hv[13]); unp2(p1.w, hv[14], hv[15]);
  float ps = 0.f, pd = 0.f;
#pragma unroll
  for (int i = 0; i < 16; ++i) { ps += as_r[i] * hv[i]; pd += ad_r[i] * hv[i]; }
#pragma unroll
  for (int m = 1; m < 16; m <<= 1) { ps += __shfl_xor(ps, m); pd += __shfl_xor(pd, m); }
  if ((lane & 15) == 0) { as_o[row * 4 + hd] = ps; ad_o[row * 4 + hd] = pd; }
}

// ---------------------------------------------------------------------------
// Per graph g: softmax over sources + head-mean aggregation + bias + relu.
// ---------------------------------------------------------------------------
__global__ __launch_bounds__(256) void attn_agg_k(const bf16* __restrict__ hbuf,
                                                  const float* __restrict__ as_i,
                                                  const float* __restrict__ ad_i,
                                                  const float* __restrict__ bgat,
                                                  __bf16* __restrict__ seq) {
  __shared__ float ass[256], ads[256], bgs[256];
  __shared__ float alpha[4][64][64];   // [hd][j][i]
  __shared__ float hq[64][260];        // one head-quarter of h, fp32
  const int g = blockIdx.x, tid = threadIdx.x;
  ass[tid] = as_i[g * 256 + tid];
  ads[tid] = ad_i[g * 256 + tid];
  bgs[tid] = bgat[tid];
  __syncthreads();
  {
    const int hd = tid >> 6, i = tid & 63;
    const float ad = ads[i * 4 + hd];
    float m = -1e30f;
    for (int j = 0; j < 64; ++j) {
      float s = ad + ass[j * 4 + hd];
      s = s > 0.0f ? s : 0.2f * s;
      m = fmaxf(m, s);
    }
    float sum = 0.0f;
    for (int j = 0; j < 64; ++j) {
      float s = ad + ass[j * 4 + hd];
      s = s > 0.0f ? s : 0.2f * s;
      sum += __expf(s - m);
    }
    const float inv = 1.0f / sum;
    for (int j = 0; j < 64; ++j) {
      float s = ad + ass[j * 4 + hd];
      s = s > 0.0f ? s : 0.2f * s;
      alpha[hd][j][i] = __expf(s - m) * inv;
    }
  }
  const int i = tid & 63, eq = tid >> 6;
  float acc[64] = {};
  for (int hd = 0; hd < 4; ++hd) {
    __syncthreads();
    for (int idx = tid; idx < 2048; idx += 256) {
      int j = idx >> 5, ch = idx & 31;
      uint4 p = *(const uint4*)(hbuf + (size_t)(g * 64 + j) * 1024 + hd * 256 + ch * 8);
      float f0, f1, f2, f3, f4, f5, f6, f7;
      unp2(p.x, f0, f1); unp2(p.y, f2, f3); unp2(p.z, f4, f5); unp2(p.w, f6, f7);
      *(float4*)&hq[j][ch * 8] = make_float4(f0, f1, f2, f3);
      *(float4*)&hq[j][ch * 8 + 4] = make_float4(f4, f5, f6, f7);
    }
    __syncthreads();
    for (int j = 0; j < 64; ++j) {
      const float a = alpha[hd][j][i];
      const float* hr = &hq[j][eq * 64];
#pragma unroll
      for (int q = 0; q < 16; ++q) {
        float4 hv = *(const float4*)(hr + q * 4);
        acc[q * 4 + 0] += a * hv.x; acc[q * 4 + 1] += a * hv.y;
        acc[q * 4 + 2] += a * hv.z; acc[q * 4 + 3] += a * hv.w;
      }
    }
  }
  __bf16* op = seq + (size_t)g * 16384 + i * 256 + eq * 64;
#pragma unroll
  for (int q = 0; q < 8; ++q) {
    float4 lo, hi;
    lo.x = fmaxf(bgs[eq * 64 + q * 8 + 0] + 0.25f * acc[q * 8 + 0], 0.0f);
    lo.y = fmaxf(bgs[eq * 64 + q * 8 + 1] + 0.25f * acc[q * 8 + 1], 0.0f);
    lo.z = fmaxf(bgs[eq * 64 + q * 8 + 2] + 0.25f * acc[q * 8 + 2], 0.0f);
    lo.w = fmaxf(bgs[eq * 64 + q * 8 + 3] + 0.25f * acc[q * 8 + 3], 0.0f);
    hi.x = fmaxf(bgs[eq * 64 + q * 8 + 4] + 0.25f * acc[q * 8 + 4], 0.0f);
    hi.y = fmaxf(bgs[eq * 64 + q * 8 + 5] + 0.25f * acc[q * 8 + 5], 0.0f);
    hi.z = fmaxf(bgs[eq * 64 + q * 8 + 6] + 0.25f * acc[q * 8 + 6], 0.0f);
    hi.w = fmaxf(bgs[eq * 64 + q * 8 + 7] + 0.25f * acc[q * 8 + 7], 0.0f);
    *(bf16x8*)(op + q * 8) = cvt8(lo, hi);
  }
}

// ---------------------------------------------------------------------------
// out[b,o] = b_fc[o] + sum_k y1[b,31,k] * Wfc[k,o]
// ---------------------------------------------------------------------------
__global__ __launch_bounds__(256) void fc_k(const float* __restrict__ y1,
                                            const float* __restrict__ Wfc,
                                            const float* __restrict__ bfc,
                                            float* __restrict__ out) {
  __shared__ float As[8][1024];
  const int tid = threadIdx.x;
  for (int idx = tid; idx < 8192; idx += 256) {
    int b = idx >> 10, k = idx & 1023;
    As[b][k] = y1[(size_t)(b * 32 + 31) * 1024 + k];
  }
  __syncthreads();
  const int ol = tid >> 2, kq = tid & 3;
  const int o = blockIdx.x * 64 + ol;
  float acc[8] = {};
  if (o < 2016) {
    for (int i2 = 0; i2 < 256; ++i2) {
      int k = i2 * 4 + kq;
      float w = Wfc[(size_t)k * 2016 + o];
#pragma unroll
      for (int b = 0; b < 8; ++b) acc[b] += As[b][k] * w;
    }
  }
#pragma unroll
  for (int b = 0; b < 8; ++b) {
    acc[b] += __shfl_xor(acc[b], 1);
    acc[b] += __shfl_xor(acc[b], 2);
  }
  if (kq == 0 && o < 2016) {
#pragma unroll
    for (int b = 0; b < 8; ++b) out[b * 2016 + o] = acc[b] + bfc[o];
  }
}

// ---------------------------------------------------------------------------
extern "C" void kernel_launch(void* const* d_in, const int* in_sizes, int n_in,
                              void* d_out, int out_size, void* d_ws, size_t ws_size,
                              hipStream_t stream) {
  (void)in_sizes; (void)n_in; (void)out_size; (void)ws_size;
  const float* x_node = (const float*)d_in[0];
  const float* x_edge = (const float*)d_in[1];
  // d_in[2] = edge_index: complete graph + self loops -> dense; unused.
  const float* W_gat = (const float*)d_in[3];
  const float* att_s = (const float*)d_in[4];
  const float* att_d = (const float*)d_in[5];
  const float* b_gat = (const float*)d_in[6];
  const float* W_ih0 = (const float*)d_in[7];
  const float* W_hh0 = (const float*)d_in[8];
  const float* b_ih0 = (const float*)d_in[9];
  const float* b_hh0 = (const float*)d_in[10];
  const float* W_ih1 = (const float*)d_in[11];
  const float* W_hh1 = (const float*)d_in[12];
  const float* b_ih1 = (const float*)d_in[13];
  const float* b_hh1 = (const float*)d_in[14];
  const float* W_fc  = (const float*)d_in[15];
  const float* b_fc  = (const float*)d_in[16];

  char* ws = (char*)d_ws;
  size_t off = 0;
  float*  he   = (float*)(ws + off);   off += 256u * 1024 * 4;          // 1 MB
  float*  a_s  = (float*)(ws + off);   off += 256u * 64 * 4 * 4;        // 256 KB
  float*  a_d  = (float*)(ws + off);   off += 256u * 64 * 4 * 4;        // 256 KB
  bf16*   hb   = (bf16*)(ws + off);    off += 256u * 64 * 1024 * 2;     // 32 MB
  __bf16* seq  = (__bf16*)(ws + off);  off += 256u * 16384 * 2;         // 8 MB
  float*  X0   = (float*)(ws + off);   off += 256u * 3072 * 4;          // 3 MB
  float*  y0   = (float*)(ws + off);   off += 256u * 1024 * 4;          // 1 MB
  float*  y1   = (float*)(ws + off);   off += 256u * 1024 * 4;          // 1 MB
  __bf16* Wb0  = (__bf16*)(ws + off);  off += 3072u * 1024 * 2;         // 6 MB
  __bf16* Wbi1 = (__bf16*)(ws + off);  off += 3072u * 1024 * 2;         // 6 MB
  __bf16* Wbh1 = (__bf16*)(ws + off);  off += 3072u * 1024 * 2;         // 6 MB
  off = (off + 255) & ~(size_t)255;
  float*  Cp   = (float*)(ws + off);   off += (size_t)16 * 256 * 3072 * 4; // 48 MB

  // 0) bf16 copies of RNN weights (once per call; L2-resident thereafter)
  wcvt_k<<<1536, 256, 0, stream>>>(W_hh0, W_ih1, W_hh1, Wb0, Wbi1, Wbh1);
  // 1) he = x_edge @ W_gat[32:, :]   (M=256, N=1024, K=2016, B is [K,N]) SK=8
  mfma_gemm_k<false><<<dim3(8, 2, 8), 256, 0, stream>>>(
      x_edge, W_gat + 32 * 1024, Cp, 256, 1024, 2016, 2016, 1024, 8);
  reduce_k<<<256, 256, 0, stream>>>(Cp, nullptr, he, 256 * 1024, 1024, 8);
  // 2) h = node-proj + he (bf16)
  node_h_k<<<dim3(4, 256), 256, 0, stream>>>(x_node, W_gat, he, hb);
  // 3) attention logits
  as_ad_k<<<4096, 256, 0, stream>>>(hb, att_s, att_d, a_s, a_d);
  // 4) softmax + aggregation + relu -> seq [256, 16384] bf16
  attn_agg_k<<<256, 256, 0, stream>>>(hb, a_s, a_d, b_gat, seq);
  // 5) X0 = seq @ W_ih0^T + b_ih0   (M=256, N=3072, K=16384) BK=64, SK=16,
  //    named-scalar prefetch (no scratch arrays), launch_bounds(256,2)
  gemm_bt64v3_k<<<dim3(24, 1, 16), 256, 0, stream>>>(seq, W_ih0, Cp,
                                                     3072, 16384, 16);
  reduce_k<<<768, 256, 0, stream>>>(Cp, b_ih0, X0, 256 * 3072, 3072, 16);
  // 6) Both GRU layers, software-pipelined (R10 best): launch t = layer0
  //    step t (256 blocks) + layer1 step t-1 (512 blocks, fused input proj).
  for (int t = 0; t <= 32; ++t)
    gru_fused2_k<<<768, 256, 0, stream>>>(X0, Wb0, b_hh0, y0,
                                          Wbi1, b_ih1, Wbh1, b_hh1, y1, t);
  // 7) out = y1[:, 31] @ W_fc + b_fc
  fc_k<<<32, 256, 0, stream>>>(y1, W_fc, b_fc, (float*)d_out);
}